// Round 3
// baseline (460.394 us; speedup 1.0000x reference)
//
#include <hip/hip_runtime.h>
#include <hip/hip_bf16.h>

// DARTS MixedOp. B=64, C=128, H=W=32. Per-sample top-k(2)-masked-softmax gate
// over 8 ops. Output 0: [64,128,32,32]; Output 1: weights clone [64,8].
//
// R2: reference dtypes are float32; R1's NaN signature is exactly what reading
// fp32 as packed bf16 produces (low halves decode to inf/NaN with p~1/256).
// This round: runtime input-dtype detection (flag in ws), dual-instantiated
// kernels guarded by the flag, fp32 output, bf16 intermediates in ws.

#define BN_SCALE 0.9999950000374997f  // 1/sqrt(1+1e-5)
#define BB 64
#define CC 128
#define HH 32
#define WW 32
#define PLANE (HH*WW)          // 1024
#define SAMP (CC*PLANE)        // 131072
#define NOUT0 (BB*SAMP)        // 8388608

__device__ __forceinline__ float us2f(unsigned int u) {
    unsigned int x = (u & 0xffffu) << 16;
    float f; __builtin_memcpy(&f, &x, 4); return f;
}
__device__ __forceinline__ unsigned short f2us(float f) {
    __hip_bfloat16 h = __float2bfloat16(f);
    unsigned short u; __builtin_memcpy(&u, &h, 2); return u;
}

// ---- input dtype adapters -------------------------------------------------
struct InF32 {
    static constexpr int FLAG = 1;
    static __device__ __forceinline__ float ld(const void* p, int i) {
        return ((const float*)p)[i];
    }
};
struct InBf16 {
    static constexpr int FLAG = 0;
    static __device__ __forceinline__ float ld(const void* p, int i) {
        return __bfloat162float(((const __hip_bfloat16*)p)[i]);
    }
};

// ---- dtype detection: low-bf16-half exponent sanity over 1024 words of x --
// fp32 data: low halves are mantissa bits -> exponent field ~uniform -> weird.
// bf16 data: low halves are real N(0,1)-ish bf16 -> exponent in [~100,150].
__device__ __forceinline__ int detect_f32(const unsigned int* xw) {
    int weird = 0;
    #pragma unroll
    for (int j = 0; j < 16; ++j) {
        unsigned int w = xw[threadIdx.x * 16 + j];
        unsigned e = (w >> 7) & 0xff;
        weird += (e != 0 && (e < 100 || e > 150)) ? 1 : 0;
    }
    #pragma unroll
    for (int off = 32; off; off >>= 1) weird += __shfl_down(weird, off);
    return __shfl(weird, 0) > 128;      // ~816 expected for fp32, ~0 for bf16
}

// ---------------------------------------------------------------- gates
template <class TI>
__global__ void k_gates(const void* __restrict__ wlog,
                        const void* __restrict__ topp,
                        const void* __restrict__ x,
                        float* __restrict__ gates, int* __restrict__ flagp,
                        float* __restrict__ out_w) {
    int isf32 = detect_f32((const unsigned int*)x);
    if (threadIdx.x == 0) *flagp = isf32;   // both instantiations write same value
    if (isf32 != TI::FLAG) return;
    int b = threadIdx.x;                    // block is exactly 64 threads

    // robust `top` parse: int32 / int64-low / fp32 / bf16
    int top = -1;
    {
        unsigned int u0 = *(const unsigned int*)topp;
        int i32 = (int)u0;
        if (i32 >= 1 && i32 <= 8) top = i32;
        else {
            float f32; __builtin_memcpy(&f32, &u0, 4);
            if (f32 >= 1.f && f32 <= 8.f) top = (int)(f32 + 0.5f);
            else { float fb = us2f(u0); if (fb >= 1.f && fb <= 8.f) top = (int)(fb + 0.5f); }
        }
        if (top < 1 || top > 8) top = 2;
    }

    float lw[8];
    #pragma unroll
    for (int i = 0; i < 8; ++i) {
        lw[i] = TI::ld(wlog, b * 8 + i);
        out_w[b * 8 + i] = lw[i];           // output 1: clone of logits (fp32)
    }
    bool sel[8] = {false,false,false,false,false,false,false,false};
    for (int t = 0; t < top; ++t) {         // lax.top_k tie-break: lowest index
        int best = -1; float bv = -3.4e38f;
        #pragma unroll
        for (int i = 0; i < 8; ++i)
            if (!sel[i] && lw[i] > bv) { bv = lw[i]; best = i; }
        if (best >= 0) sel[best] = true;
    }
    float m = -3.4e38f;
    #pragma unroll
    for (int i = 0; i < 8; ++i) if (sel[i] && lw[i] > m) m = lw[i];
    float s = 0.f, e[8];
    #pragma unroll
    for (int i = 0; i < 8; ++i) { e[i] = sel[i] ? expf(lw[i] - m) : 0.f; s += e[i]; }
    if (!(s > 0.f)) {                       // NaN-proof fallback
        float u = 1.f / (float)top;
        #pragma unroll
        for (int i = 0; i < 8; ++i) gates[b * 8 + i] = sel[i] ? u : 0.f;
        return;
    }
    float inv = 1.f / s;
    #pragma unroll
    for (int i = 0; i < 8; ++i) gates[b * 8 + i] = e[i] * inv;
}

// ------------------------------------------- pools + skip + out init (fp32)
template <class TI>
__global__ void k_pools(const void* __restrict__ x,
                        const float* __restrict__ gates,
                        const int* __restrict__ flagp,
                        float* __restrict__ out) {
    if (*flagp != TI::FLAG) return;
    int plane = blockIdx.x;            // b*128 + c
    int b = plane >> 7;
    float g1 = gates[b * 8 + 1] * BN_SCALE;   // max_pool_3x3 -> BN
    float g2 = gates[b * 8 + 2] * BN_SCALE;   // avg_pool_3x3 -> BN
    float g3 = gates[b * 8 + 3];              // skip
    int base = plane * PLANE;
    float* op = out + base;
    #pragma unroll
    for (int j = 0; j < 4; ++j) {
        int px = threadIdx.x + j * 256;
        int h = px >> 5, w = px & 31;
        float xc = TI::ld(x, base + px);
        float mx = -3.4e38f, sm = 0.f;
        int cnt = 0;
        #pragma unroll
        for (int dh = -1; dh <= 1; ++dh) {
            int ih = h + dh;
            if ((unsigned)ih >= HH) continue;
            #pragma unroll
            for (int dw = -1; dw <= 1; ++dw) {
                int iw = w + dw;
                if ((unsigned)iw >= WW) continue;
                float v = TI::ld(x, base + ih * WW + iw);
                mx = fmaxf(mx, v);
                sm += v;
                ++cnt;
            }
        }
        op[px] = g1 * mx + g2 * (sm / (float)cnt) + g3 * xc;
    }
}

// ---------------------------------------------------------------- dw conv
// relu on input. XSRC: input is the external x (dtype TI); else bf16 tmp.
template <class TI, int K, int DIL, bool XSRC>
__global__ void k_dw(const void* __restrict__ in,
                     const void* __restrict__ wd,
                     const float* __restrict__ gates,
                     const int* __restrict__ flagp, int op,
                     __hip_bfloat16* __restrict__ outp) {
    if (*flagp != TI::FLAG) return;
    int plane = blockIdx.x;            // b*128 + c
    int b = plane >> 7, c = plane & 127;
    if (gates[b * 8 + op] == 0.f) return;
    constexpr int PAD = (K / 2) * DIL;
    float wk[K * K];
    #pragma unroll
    for (int i = 0; i < K * K; ++i) wk[i] = TI::ld(wd, c * K * K + i);
    int base = plane * PLANE;
    const __hip_bfloat16* ipb = (const __hip_bfloat16*)in + base;
    __hip_bfloat16* opp = outp + base;
    #pragma unroll
    for (int j = 0; j < 4; ++j) {
        int px = threadIdx.x + j * 256;
        int h = px >> 5, w = px & 31;
        float acc = 0.f;
        #pragma unroll
        for (int ky = 0; ky < K; ++ky) {
            int ih = h + ky * DIL - PAD;
            if ((unsigned)ih >= HH) continue;
            #pragma unroll
            for (int kx = 0; kx < K; ++kx) {
                int iw = w + kx * DIL - PAD;
                if ((unsigned)iw >= WW) continue;
                float v = XSRC ? TI::ld(in, base + ih * WW + iw)
                               : __bfloat162float(ipb[ih * WW + iw]);
                acc = fmaf(wk[ky * K + kx], fmaxf(v, 0.f), acc);
            }
        }
        opp[px] = __float2bfloat16(acc);
    }
}

// ---------------------------------------------------------------- pw 1x1 conv
// in: bf16 tmp (always). W: dtype TI. FINAL: out0 fp32 RMW; else bf16 tmp.
template <class TI, bool FINAL>
__global__ void k_pw(const __hip_bfloat16* __restrict__ in,
                     const void* __restrict__ W,
                     const float* __restrict__ gates,
                     const int* __restrict__ flagp, int op,
                     void* __restrict__ outp) {
    if (*flagp != TI::FLAG) return;
    int blk = blockIdx.x;              // b*32 + cog*2 + hws
    int hws = blk & 1;
    int cog = (blk >> 1) & 15;
    int b = blk >> 5;
    float g = gates[b * 8 + op];
    if (g == 0.f) return;
    int co0 = cog * 8;
    int hw = hws * 512 + threadIdx.x * 2;
    const __hip_bfloat16* ib = in + (size_t)b * SAMP;
    float2 acc[8];
    #pragma unroll
    for (int k = 0; k < 8; ++k) acc[k] = make_float2(0.f, 0.f);
    for (int ci = 0; ci < CC; ++ci) {
        unsigned int raw = *reinterpret_cast<const unsigned int*>(ib + ci * PLANE + hw);
        float vx = us2f(raw), vy = us2f(raw >> 16);
        #pragma unroll
        for (int k = 0; k < 8; ++k) {
            float wv = TI::ld(W, (co0 + k) * CC + ci);   // block-uniform -> scalar
            acc[k].x = fmaf(wv, vx, acc[k].x);
            acc[k].y = fmaf(wv, vy, acc[k].y);
        }
    }
    if (FINAL) {
        float gs = g * BN_SCALE;
        float* ob = (float*)outp;
        #pragma unroll
        for (int k = 0; k < 8; ++k) {
            size_t idx = (size_t)(b * CC + co0 + k) * PLANE + hw;
            float2* p = reinterpret_cast<float2*>(ob + idx);
            float2 o = *p;
            o.x += gs * acc[k].x;
            o.y += gs * acc[k].y;
            *p = o;
        }
    } else {
        __hip_bfloat16* ob = (__hip_bfloat16*)outp;
        #pragma unroll
        for (int k = 0; k < 8; ++k) {
            size_t idx = (size_t)(b * CC + co0 + k) * PLANE + hw;
            unsigned int* p = reinterpret_cast<unsigned int*>(ob + idx);
            *p = (unsigned int)f2us(BN_SCALE * acc[k].x) |
                 ((unsigned int)f2us(BN_SCALE * acc[k].y) << 16);
        }
    }
}

// ---------------------------------------------------------------- launch
template <class TI>
static void launch_all(const void* x, const void* wlog, const void* topp,
                       const void* p[12], float* gates, int* flagp,
                       float* out, float* outw,
                       __hip_bfloat16* tmp1, __hip_bfloat16* tmp2,
                       hipStream_t stream) {
    k_gates<TI><<<1, 64, 0, stream>>>(wlog, topp, x, gates, flagp, outw);
    k_pools<TI><<<BB * CC, 256, 0, stream>>>(x, gates, flagp, out);

    // op4: sep_conv_3x3 = (relu-dw3-pw-BN) x2
    k_dw<TI, 3, 1, true ><<<BB * CC, 256, 0, stream>>>(x,    p[0], gates, flagp, 4, tmp1);
    k_pw<TI, false><<<BB * 32, 256, 0, stream>>>(tmp1, p[1], gates, flagp, 4, tmp2);
    k_dw<TI, 3, 1, false><<<BB * CC, 256, 0, stream>>>(tmp2, p[2], gates, flagp, 4, tmp1);
    k_pw<TI, true ><<<BB * 32, 256, 0, stream>>>(tmp1, p[3], gates, flagp, 4, out);
    // op5: sep_conv_5x5
    k_dw<TI, 5, 1, true ><<<BB * CC, 256, 0, stream>>>(x,    p[4], gates, flagp, 5, tmp1);
    k_pw<TI, false><<<BB * 32, 256, 0, stream>>>(tmp1, p[5], gates, flagp, 5, tmp2);
    k_dw<TI, 5, 1, false><<<BB * CC, 256, 0, stream>>>(tmp2, p[6], gates, flagp, 5, tmp1);
    k_pw<TI, true ><<<BB * 32, 256, 0, stream>>>(tmp1, p[7], gates, flagp, 5, out);
    // op6: dil_conv_3x3 (dil=2)
    k_dw<TI, 3, 2, true ><<<BB * CC, 256, 0, stream>>>(x,    p[8], gates, flagp, 6, tmp1);
    k_pw<TI, true ><<<BB * 32, 256, 0, stream>>>(tmp1, p[9], gates, flagp, 6, out);
    // op7: dil_conv_5x5 (dil=2)
    k_dw<TI, 5, 2, true ><<<BB * CC, 256, 0, stream>>>(x,    p[10], gates, flagp, 7, tmp1);
    k_pw<TI, true ><<<BB * 32, 256, 0, stream>>>(tmp1, p[11], gates, flagp, 7, out);
}

extern "C" void kernel_launch(void* const* d_in, const int* in_sizes, int n_in,
                              void* d_out, int out_size, void* d_ws, size_t ws_size,
                              hipStream_t stream) {
    const void* x    = d_in[0];
    const void* wlog = d_in[1];
    const void* prm[12] = { d_in[2], d_in[3], d_in[4], d_in[5],
                            d_in[6], d_in[7], d_in[8], d_in[9],
                            d_in[10], d_in[11], d_in[12], d_in[13] };
    const void* topp = d_in[14];

    float* out  = (float*)d_out;
    float* outw = out + NOUT0;

    float* gates = (float*)d_ws;                                  // 2 KB
    int*   flagp = (int*)((char*)d_ws + 2048);
    __hip_bfloat16* tmp1 = (__hip_bfloat16*)((char*)d_ws + 4096); // 16.8 MB
    __hip_bfloat16* tmp2 = tmp1 + NOUT0;                          // 16.8 MB

    launch_all<InF32 >(x, wlog, topp, prm, gates, flagp, out, outw, tmp1, tmp2, stream);
    launch_all<InBf16>(x, wlog, topp, prm, gates, flagp, out, outw, tmp1, tmp2, stream);
}

// Round 5
// 317.403 us; speedup vs baseline: 1.4505x; 1.4505x over previous
//
#include <hip/hip_runtime.h>
#include <hip/hip_bf16.h>

// DARTS MixedOp. B=64, C=128, H=W=32. Per-sample top-k(2) masked-softmax gate
// over 8 ops. Outputs: [64,128,32,32] fp32 + weights clone [64,8] fp32.
//
// Dtype facts (R3 vs R4 A/B): inputs fp32 (R3's runtime detector chose the
// fp32 path and passed; R4 bf16-only NaN'd -> fp32 confirmed). Outputs fp32.
// R3's k_pools FETCH=16.4MB was LLC-absorbed fp32 (33.6MB), not bf16.
//
// R5: single fp32 path; k_pools zero-fast-path + LDS float4; k_dw LDS-staged
// with fused relu; bf16 intermediates in ws (absmax 0.0156 << 0.099 thr).

#define BN_SCALE 0.9999950000374997f  // 1/sqrt(1+1e-5)
#define BB 64
#define CC 128
#define HH 32
#define WW 32
#define PLANE (HH*WW)          // 1024
#define SAMP (CC*PLANE)        // 131072
#define NOUT0 (BB*SAMP)        // 8388608

__device__ __forceinline__ float us2f(unsigned int u) {
    unsigned int x = (u & 0xffffu) << 16;
    float f; __builtin_memcpy(&f, &x, 4); return f;
}
__device__ __forceinline__ unsigned short f2us(float f) {
    __hip_bfloat16 h = __float2bfloat16(f);
    unsigned short u; __builtin_memcpy(&u, &h, 2); return u;
}

// ---------------------------------------------------------------- gates
__global__ void k_gates(const float* __restrict__ wlog,
                        const void* __restrict__ topp,
                        float* __restrict__ gates,
                        float* __restrict__ out_w) {
    int b = threadIdx.x;                    // block is exactly 64 threads

    // robust `top` parse: int32 / int64-low / fp32 / bf16
    int top = -1;
    {
        unsigned int u0 = *(const unsigned int*)topp;
        int i32 = (int)u0;
        if (i32 >= 1 && i32 <= 8) top = i32;
        else {
            float f32; __builtin_memcpy(&f32, &u0, 4);
            if (f32 >= 1.f && f32 <= 8.f) top = (int)(f32 + 0.5f);
            else { float fb = us2f(u0); if (fb >= 1.f && fb <= 8.f) top = (int)(fb + 0.5f); }
        }
        if (top < 1 || top > 8) top = 2;
    }

    float lw[8];
    #pragma unroll
    for (int i = 0; i < 8; ++i) {
        lw[i] = wlog[b * 8 + i];
        out_w[b * 8 + i] = lw[i];           // output 1: clone of logits
    }
    bool sel[8] = {false,false,false,false,false,false,false,false};
    for (int t = 0; t < top; ++t) {         // lax.top_k tie-break: lowest index
        int best = -1; float bv = -3.4e38f;
        #pragma unroll
        for (int i = 0; i < 8; ++i)
            if (!sel[i] && lw[i] > bv) { bv = lw[i]; best = i; }
        if (best >= 0) sel[best] = true;
    }
    float m = -3.4e38f;
    #pragma unroll
    for (int i = 0; i < 8; ++i) if (sel[i] && lw[i] > m) m = lw[i];
    float s = 0.f, e[8];
    #pragma unroll
    for (int i = 0; i < 8; ++i) { e[i] = sel[i] ? expf(lw[i] - m) : 0.f; s += e[i]; }
    if (!(s > 0.f)) {                       // NaN-proof fallback
        float u = 1.f / (float)top;
        #pragma unroll
        for (int i = 0; i < 8; ++i) gates[b * 8 + i] = sel[i] ? u : 0.f;
        return;
    }
    float inv = 1.f / s;
    #pragma unroll
    for (int i = 0; i < 8; ++i) gates[b * 8 + i] = e[i] * inv;
}

// ------------------------------------------- pools + skip + out init (fp32)
__global__ __launch_bounds__(256) void
k_pools(const float* __restrict__ x,
        const float* __restrict__ gates,
        float* __restrict__ out) {
    int plane = blockIdx.x;            // b*128 + c
    int b = plane >> 7;
    float g1 = gates[b * 8 + 1] * BN_SCALE;   // max_pool_3x3 -> BN
    float g2 = gates[b * 8 + 2] * BN_SCALE;   // avg_pool_3x3 -> BN
    float g3 = gates[b * 8 + 3];              // skip
    float* op = out + (size_t)plane * PLANE;
    if (g1 == 0.f && g2 == 0.f && g3 == 0.f) {
        ((float4*)op)[threadIdx.x] = make_float4(0.f, 0.f, 0.f, 0.f);
        return;
    }
    __shared__ float sx[PLANE];
    ((float4*)sx)[threadIdx.x] = ((const float4*)(x + (size_t)plane * PLANE))[threadIdx.x];
    __syncthreads();
    #pragma unroll
    for (int j = 0; j < 4; ++j) {
        int px = threadIdx.x + j * 256;
        int h = px >> 5, w = px & 31;
        float mx = -3.4e38f, sm = 0.f;
        int cnt = 0;
        #pragma unroll
        for (int dh = -1; dh <= 1; ++dh) {
            int ih = h + dh;
            if ((unsigned)ih >= HH) continue;
            #pragma unroll
            for (int dw = -1; dw <= 1; ++dw) {
                int iw = w + dw;
                if ((unsigned)iw >= WW) continue;
                float v = sx[ih * WW + iw];
                mx = fmaxf(mx, v);
                sm += v;
                ++cnt;
            }
        }
        op[px] = g1 * mx + g2 * (sm / (float)cnt) + g3 * sx[px];
    }
}

// ---------------------------------------------------------------- dw conv
// relu applied at LDS stage (reference: dw(relu(.))).
// XSRC=true: input is x (fp32). XSRC=false: input is bf16 tmp.
template <int K, int DIL, bool XSRC>
__global__ __launch_bounds__(256) void
k_dw(const void* __restrict__ in,
     const float* __restrict__ wd,
     const float* __restrict__ gates, int op,
     unsigned short* __restrict__ outp) {
    int plane = blockIdx.x;            // b*128 + c
    int b = plane >> 7, c = plane & 127;
    if (gates[b * 8 + op] == 0.f) return;
    constexpr int PAD = (K / 2) * DIL;
    float wk[K * K];
    #pragma unroll
    for (int i = 0; i < K * K; ++i) wk[i] = wd[c * K * K + i];
    __shared__ float sx[PLANE];
    if (XSRC) {
        float4 v = ((const float4*)((const float*)in + (size_t)plane * PLANE))[threadIdx.x];
        ((float4*)sx)[threadIdx.x] =
            make_float4(fmaxf(v.x, 0.f), fmaxf(v.y, 0.f),
                        fmaxf(v.z, 0.f), fmaxf(v.w, 0.f));
    } else {
        ushort4 v = ((const ushort4*)((const unsigned short*)in + (size_t)plane * PLANE))[threadIdx.x];
        ((float4*)sx)[threadIdx.x] =
            make_float4(fmaxf(us2f(v.x), 0.f), fmaxf(us2f(v.y), 0.f),
                        fmaxf(us2f(v.z), 0.f), fmaxf(us2f(v.w), 0.f));
    }
    __syncthreads();
    unsigned short* opp = outp + (size_t)plane * PLANE;
    #pragma unroll
    for (int j = 0; j < 4; ++j) {
        int px = threadIdx.x + j * 256;
        int h = px >> 5, w = px & 31;
        float acc = 0.f;
        #pragma unroll
        for (int ky = 0; ky < K; ++ky) {
            int ih = h + ky * DIL - PAD;
            if ((unsigned)ih >= HH) continue;
            #pragma unroll
            for (int kx = 0; kx < K; ++kx) {
                int iw = w + kx * DIL - PAD;
                if ((unsigned)iw >= WW) continue;
                acc = fmaf(wk[ky * K + kx], sx[ih * WW + iw], acc);
            }
        }
        opp[px] = f2us(acc);
    }
}

// ---------------------------------------------------------------- pw 1x1 conv
// in: bf16 tmp. W: fp32 (block-uniform scalar loads). FINAL: fp32 RMW on out0;
// else bf16 tmp. Block: (b, co-tile of 8, hw-half of 512). 256 thr x 2 hw.
template <bool FINAL>
__global__ __launch_bounds__(256) void
k_pw(const unsigned short* __restrict__ in,
     const float* __restrict__ W,
     const float* __restrict__ gates, int op,
     void* __restrict__ outp) {
    int blk = blockIdx.x;              // b*32 + cog*2 + hws
    int hws = blk & 1;
    int cog = (blk >> 1) & 15;
    int b = blk >> 5;
    float g = gates[b * 8 + op];
    if (g == 0.f) return;
    int co0 = cog * 8;
    int hw = hws * 512 + threadIdx.x * 2;
    const unsigned short* ib = in + (size_t)b * SAMP;
    float2 acc[8];
    #pragma unroll
    for (int k = 0; k < 8; ++k) acc[k] = make_float2(0.f, 0.f);
    for (int ci = 0; ci < CC; ++ci) {
        unsigned int raw = *reinterpret_cast<const unsigned int*>(ib + ci * PLANE + hw);
        float vx = us2f(raw), vy = us2f(raw >> 16);
        #pragma unroll
        for (int k = 0; k < 8; ++k) {
            float wv = W[(co0 + k) * CC + ci];   // block-uniform -> scalar load
            acc[k].x = fmaf(wv, vx, acc[k].x);
            acc[k].y = fmaf(wv, vy, acc[k].y);
        }
    }
    if (FINAL) {
        float gs = g * BN_SCALE;
        float* ob = (float*)outp;
        #pragma unroll
        for (int k = 0; k < 8; ++k) {
            size_t idx = (size_t)(b * CC + co0 + k) * PLANE + hw;
            float2* p = reinterpret_cast<float2*>(ob + idx);
            float2 o = *p;
            o.x += gs * acc[k].x;
            o.y += gs * acc[k].y;
            *p = o;
        }
    } else {
        unsigned short* ob = (unsigned short*)outp;
        #pragma unroll
        for (int k = 0; k < 8; ++k) {
            size_t idx = (size_t)(b * CC + co0 + k) * PLANE + hw;
            unsigned int* p = reinterpret_cast<unsigned int*>(ob + idx);
            *p = (unsigned int)f2us(BN_SCALE * acc[k].x) |
                 ((unsigned int)f2us(BN_SCALE * acc[k].y) << 16);
        }
    }
}

// ---------------------------------------------------------------- launch
extern "C" void kernel_launch(void* const* d_in, const int* in_sizes, int n_in,
                              void* d_out, int out_size, void* d_ws, size_t ws_size,
                              hipStream_t stream) {
    const float* x      = (const float*)d_in[0];
    const float* wlog   = (const float*)d_in[1];
    const float* sc3_d1 = (const float*)d_in[2];
    const float* sc3_p1 = (const float*)d_in[3];
    const float* sc3_d2 = (const float*)d_in[4];
    const float* sc3_p2 = (const float*)d_in[5];
    const float* sc5_d1 = (const float*)d_in[6];
    const float* sc5_p1 = (const float*)d_in[7];
    const float* sc5_d2 = (const float*)d_in[8];
    const float* sc5_p2 = (const float*)d_in[9];
    const float* dc3_d  = (const float*)d_in[10];
    const float* dc3_p  = (const float*)d_in[11];
    const float* dc5_d  = (const float*)d_in[12];
    const float* dc5_p  = (const float*)d_in[13];
    const void* topp    = d_in[14];

    float* out  = (float*)d_out;
    float* outw = out + NOUT0;

    float* gates = (float*)d_ws;                                  // 2 KB
    unsigned short* tmp1 = (unsigned short*)((char*)d_ws + 4096); // 16.8 MB
    unsigned short* tmp2 = tmp1 + NOUT0;                          // 16.8 MB

    k_gates<<<1, 64, 0, stream>>>(wlog, topp, gates, outw);
    k_pools<<<BB * CC, 256, 0, stream>>>(x, gates, out);

    // op4: sep_conv_3x3 = (relu-dw3-pw-BN) x2
    k_dw<3, 1, true ><<<BB * CC, 256, 0, stream>>>(x,    sc3_d1, gates, 4, tmp1);
    k_pw<false><<<BB * 32, 256, 0, stream>>>(tmp1, sc3_p1, gates, 4, tmp2);
    k_dw<3, 1, false><<<BB * CC, 256, 0, stream>>>(tmp2, sc3_d2, gates, 4, tmp1);
    k_pw<true ><<<BB * 32, 256, 0, stream>>>(tmp1, sc3_p2, gates, 4, out);
    // op5: sep_conv_5x5
    k_dw<5, 1, true ><<<BB * CC, 256, 0, stream>>>(x,    sc5_d1, gates, 5, tmp1);
    k_pw<false><<<BB * 32, 256, 0, stream>>>(tmp1, sc5_p1, gates, 5, tmp2);
    k_dw<5, 1, false><<<BB * CC, 256, 0, stream>>>(tmp2, sc5_d2, gates, 5, tmp1);
    k_pw<true ><<<BB * 32, 256, 0, stream>>>(tmp1, sc5_p2, gates, 5, out);
    // op6: dil_conv_3x3 (dil=2, pad=2)
    k_dw<3, 2, true ><<<BB * CC, 256, 0, stream>>>(x,    dc3_d, gates, 6, tmp1);
    k_pw<true ><<<BB * 32, 256, 0, stream>>>(tmp1, dc3_p, gates, 6, out);
    // op7: dil_conv_5x5 (dil=2, pad=4)
    k_dw<5, 2, true ><<<BB * CC, 256, 0, stream>>>(x,    dc5_d, gates, 7, tmp1);
    k_pw<true ><<<BB * 32, 256, 0, stream>>>(tmp1, dc5_p, gates, 7, out);
}

// Round 6
// 209.414 us; speedup vs baseline: 2.1985x; 1.5157x over previous
//
#include <hip/hip_runtime.h>
#include <hip/hip_bf16.h>

// DARTS MixedOp. B=64, C=128, H=W=32. Per-sample top-k(2) masked-softmax gate
// over 8 ops. Inputs fp32 (R3/R4 A/B-confirmed), outputs fp32.
//
// R6: 14 -> 5 dispatches. Gating kills ~75% of blocks in per-op dispatches
// (2 waves/SIMD, latency-bound); merging ops into shared dispatches restores
// occupancy and removes launch gaps. k_pw_final fuses pools+skip+init+final
// pointwise convs: register accumulation, single out write (no RMW).
//
// ws layout: gates[64*8] f32 @0 | cnum[64] i32 @2048 | cops[64*2] i32 @2304 |
// 8 bf16 buffers of 16.8MB @4096 (A4 A5 B4 B5 P4 P5 P6 P7). ~134MB < ws.

#define BN_SCALE 0.9999950000374997f  // 1/sqrt(1+1e-5)
#define BB 64
#define CC 128
#define HH 32
#define WW 32
#define PLANE (HH*WW)          // 1024
#define SAMP (CC*PLANE)        // 131072
#define NOUT0 (BB*SAMP)        // 8388608

__device__ __forceinline__ float us2f(unsigned int u) {
    unsigned int x = (u & 0xffffu) << 16;
    float f; __builtin_memcpy(&f, &x, 4); return f;
}
__device__ __forceinline__ unsigned short f2us(float f) {
    __hip_bfloat16 h = __float2bfloat16(f);
    unsigned short u; __builtin_memcpy(&u, &h, 2); return u;
}

// ---------------------------------------------------------------- gates
__global__ void k_gates(const float* __restrict__ wlog,
                        const void* __restrict__ topp,
                        float* __restrict__ gates,
                        int* __restrict__ cnum, int* __restrict__ cops,
                        float* __restrict__ out_w) {
    int b = threadIdx.x;                    // block is exactly 64 threads

    // robust `top` parse: int32 / int64-low / fp32 / bf16
    int top = -1;
    {
        unsigned int u0 = *(const unsigned int*)topp;
        int i32 = (int)u0;
        if (i32 >= 1 && i32 <= 8) top = i32;
        else {
            float f32; __builtin_memcpy(&f32, &u0, 4);
            if (f32 >= 1.f && f32 <= 8.f) top = (int)(f32 + 0.5f);
            else { float fb = us2f(u0); if (fb >= 1.f && fb <= 8.f) top = (int)(fb + 0.5f); }
        }
        if (top < 1 || top > 8) top = 2;
    }

    float lw[8];
    #pragma unroll
    for (int i = 0; i < 8; ++i) {
        lw[i] = wlog[b * 8 + i];
        out_w[b * 8 + i] = lw[i];           // output 1: clone of logits
    }
    bool sel[8] = {false,false,false,false,false,false,false,false};
    for (int t = 0; t < top; ++t) {         // lax.top_k tie-break: lowest index
        int best = -1; float bv = -3.4e38f;
        #pragma unroll
        for (int i = 0; i < 8; ++i)
            if (!sel[i] && lw[i] > bv) { bv = lw[i]; best = i; }
        if (best >= 0) sel[best] = true;
    }
    float m = -3.4e38f;
    #pragma unroll
    for (int i = 0; i < 8; ++i) if (sel[i] && lw[i] > m) m = lw[i];
    float s = 0.f, e[8];
    #pragma unroll
    for (int i = 0; i < 8; ++i) { e[i] = sel[i] ? expf(lw[i] - m) : 0.f; s += e[i]; }
    float inv = (s > 0.f) ? 1.f / s : 0.f;
    float g[8];
    #pragma unroll
    for (int i = 0; i < 8; ++i) {
        g[i] = (s > 0.f) ? e[i] * inv : (sel[i] ? 1.f / (float)top : 0.f);
        gates[b * 8 + i] = g[i];
    }
    // compacted conv-op list (ops 4..7 with gate>0)
    int n = 0;
    #pragma unroll
    for (int i = 4; i < 8; ++i)
        if (g[i] > 0.f) { cops[b * 2 + (n < 2 ? n : 1)] = i; ++n; }
    cnum[b] = (n < 2) ? n : 2;              // top-2 => at most 2
}

// ------------------------------------------- depthwise conv helper
template <int K, int DIL>
__device__ __forceinline__ void dw_comp(const float* __restrict__ sx,
                                        const float* __restrict__ wd, int c,
                                        unsigned short* __restrict__ opp) {
    constexpr int PAD = (K / 2) * DIL;
    float wk[K * K];
    #pragma unroll
    for (int i = 0; i < K * K; ++i) wk[i] = wd[c * K * K + i];
    #pragma unroll
    for (int j = 0; j < 4; ++j) {
        int px = threadIdx.x + j * 256;
        int h = px >> 5, w = px & 31;
        float acc = 0.f;
        #pragma unroll
        for (int ky = 0; ky < K; ++ky) {
            int ih = h + ky * DIL - PAD;
            if ((unsigned)ih >= HH) continue;
            #pragma unroll
            for (int kx = 0; kx < K; ++kx) {
                int iw = w + kx * DIL - PAD;
                if ((unsigned)iw >= WW) continue;
                acc = fmaf(wk[ky * K + kx], sx[ih * WW + iw], acc);
            }
        }
        opp[px] = f2us(acc);
    }
}

// ---------------------------------- first dw for all 4 conv ops (from x)
__global__ __launch_bounds__(256) void
k_dw_first(const float* __restrict__ x,
           const float* __restrict__ w4, const float* __restrict__ w5,
           const float* __restrict__ w6, const float* __restrict__ w7,
           const float* __restrict__ gates,
           unsigned short* __restrict__ A4, unsigned short* __restrict__ A5,
           unsigned short* __restrict__ P6, unsigned short* __restrict__ P7) {
    int plane = blockIdx.x;            // b*128 + c
    int b = plane >> 7, c = plane & 127;
    float g4 = gates[b * 8 + 4], g5 = gates[b * 8 + 5];
    float g6 = gates[b * 8 + 6], g7 = gates[b * 8 + 7];
    if (g4 == 0.f && g5 == 0.f && g6 == 0.f && g7 == 0.f) return;
    __shared__ float sx[PLANE];
    {
        float4 v = ((const float4*)(x + (size_t)plane * PLANE))[threadIdx.x];
        ((float4*)sx)[threadIdx.x] =
            make_float4(fmaxf(v.x, 0.f), fmaxf(v.y, 0.f),
                        fmaxf(v.z, 0.f), fmaxf(v.w, 0.f));
    }
    __syncthreads();
    size_t off = (size_t)plane * PLANE;
    if (g4 != 0.f) dw_comp<3, 1>(sx, w4, c, A4 + off);
    if (g5 != 0.f) dw_comp<5, 1>(sx, w5, c, A5 + off);
    if (g6 != 0.f) dw_comp<3, 2>(sx, w6, c, P6 + off);
    if (g7 != 0.f) dw_comp<5, 2>(sx, w7, c, P7 + off);
}

// ---------------------------------- second dw for sep ops (from bufB)
__global__ __launch_bounds__(256) void
k_dw_second(const unsigned short* __restrict__ B4,
            const unsigned short* __restrict__ B5,
            const float* __restrict__ w4, const float* __restrict__ w5,
            const float* __restrict__ gates,
            unsigned short* __restrict__ P4, unsigned short* __restrict__ P5) {
    int plane = blockIdx.x;            // b*128 + c
    int b = plane >> 7, c = plane & 127;
    float g4 = gates[b * 8 + 4], g5 = gates[b * 8 + 5];
    if (g4 == 0.f && g5 == 0.f) return;
    __shared__ float sx[PLANE];
    size_t off = (size_t)plane * PLANE;
    if (g4 != 0.f) {                       // block-uniform branch
        ushort4 v = ((const ushort4*)(B4 + off))[threadIdx.x];
        ((float4*)sx)[threadIdx.x] =
            make_float4(fmaxf(us2f(v.x), 0.f), fmaxf(us2f(v.y), 0.f),
                        fmaxf(us2f(v.z), 0.f), fmaxf(us2f(v.w), 0.f));
        __syncthreads();
        dw_comp<3, 1>(sx, w4, c, P4 + off);
        __syncthreads();
    }
    if (g5 != 0.f) {
        ushort4 v = ((const ushort4*)(B5 + off))[threadIdx.x];
        ((float4*)sx)[threadIdx.x] =
            make_float4(fmaxf(us2f(v.x), 0.f), fmaxf(us2f(v.y), 0.f),
                        fmaxf(us2f(v.z), 0.f), fmaxf(us2f(v.w), 0.f));
        __syncthreads();
        dw_comp<5, 1>(sx, w5, c, P5 + off);
    }
}

// ------------------------------------------- pw K-loop (shared)
__device__ __forceinline__ void pw_acc(const unsigned short* __restrict__ ib,
                                       const float* __restrict__ W,
                                       int co0, int hw, float2* acc) {
    for (int ci = 0; ci < CC; ++ci) {
        unsigned int raw = *reinterpret_cast<const unsigned int*>(ib + ci * PLANE + hw);
        float vx = us2f(raw), vy = us2f(raw >> 16);
        #pragma unroll
        for (int k = 0; k < 8; ++k) {
            float wv = W[(co0 + k) * CC + ci];   // block-uniform -> scalar load
            acc[k].x = fmaf(wv, vx, acc[k].x);
            acc[k].y = fmaf(wv, vy, acc[k].y);
        }
    }
}

// ---------------------------------- mid pw for sep ops 4,5 (A -> B, *BN)
__global__ __launch_bounds__(256) void
k_pw_mid(const unsigned short* __restrict__ A4,
         const unsigned short* __restrict__ A5,
         const float* __restrict__ W4, const float* __restrict__ W5,
         const float* __restrict__ gates,
         unsigned short* __restrict__ B4, unsigned short* __restrict__ B5) {
    int blk = blockIdx.x;              // (opi*64 + b)*32 + cog*2 + hws
    int hws = blk & 1;
    int cog = (blk >> 1) & 15;
    int b   = (blk >> 5) & 63;
    int opi = blk >> 11;
    float g = gates[b * 8 + 4 + opi];
    if (g == 0.f) return;
    const unsigned short* in = (opi ? A5 : A4) + (size_t)b * SAMP;
    const float* W = opi ? W5 : W4;
    unsigned short* ob = (opi ? B5 : B4);
    int co0 = cog * 8;
    int hw = hws * 512 + threadIdx.x * 2;
    float2 acc[8];
    #pragma unroll
    for (int k = 0; k < 8; ++k) acc[k] = make_float2(0.f, 0.f);
    pw_acc(in, W, co0, hw, acc);
    #pragma unroll
    for (int k = 0; k < 8; ++k) {
        size_t idx = (size_t)(b * CC + co0 + k) * PLANE + hw;
        unsigned int* p = reinterpret_cast<unsigned int*>(ob + idx);
        *p = (unsigned int)f2us(BN_SCALE * acc[k].x) |
             ((unsigned int)f2us(BN_SCALE * acc[k].y) << 16);
    }
}

// ------------- final: pools + skip + gated final pw, single out write
__global__ __launch_bounds__(256) void
k_pw_final(const float* __restrict__ x,
           const unsigned short* __restrict__ P4,
           const unsigned short* __restrict__ P5,
           const unsigned short* __restrict__ P6,
           const unsigned short* __restrict__ P7,
           const float* __restrict__ W4, const float* __restrict__ W5,
           const float* __restrict__ W6, const float* __restrict__ W7,
           const float* __restrict__ gates,
           const int* __restrict__ cnum, const int* __restrict__ cops,
           float* __restrict__ out) {
    int blk = blockIdx.x;              // b*32 + cog*2 + hws
    int hws = blk & 1;
    int cog = (blk >> 1) & 15;
    int b = blk >> 5;
    int co0 = cog * 8;
    int hw = hws * 512 + threadIdx.x * 2;

    float g1 = gates[b * 8 + 1] * BN_SCALE;   // max_pool -> BN
    float g2 = gates[b * 8 + 2] * BN_SCALE;   // avg_pool -> BN
    float g3 = gates[b * 8 + 3];              // skip
    bool haspool = (g1 != 0.f) | (g2 != 0.f) | (g3 != 0.f);

    // stage x tile for pools/skip: 8 ch x 18 rows x 32 cols
    __shared__ float sxp[8 * 18 * 32];
    int r0 = hws * 16;
    if (haspool) {                            // block-uniform
        for (int li = threadIdx.x; li < 8 * 18 * 8; li += 256) {
            int ch = li / 144, rem = li - ch * 144;
            int row = rem >> 3, c4 = rem & 7;
            int gr = r0 + row - 1;
            if ((unsigned)gr < HH) {
                float4 v = *(const float4*)(x + ((size_t)(b * CC + co0 + ch) * HH + gr) * WW + c4 * 4);
                *(float4*)(sxp + (ch * 18 + row) * 32 + c4 * 4) = v;
            }
        }
        __syncthreads();
    }

    // gated final pointwise convs (at most 2), register accumulation
    float2 acc[8];
    #pragma unroll
    for (int k = 0; k < 8; ++k) acc[k] = make_float2(0.f, 0.f);
    int n = cnum[b];
    for (int t = 0; t < n; ++t) {
        int op = cops[b * 2 + t];
        float gs = gates[b * 8 + op] * BN_SCALE;
        const unsigned short* src;
        const float* W;
        switch (op) {
            case 4:  src = P4; W = W4; break;
            case 5:  src = P5; W = W5; break;
            case 6:  src = P6; W = W6; break;
            default: src = P7; W = W7; break;
        }
        float2 a2[8];
        #pragma unroll
        for (int k = 0; k < 8; ++k) a2[k] = make_float2(0.f, 0.f);
        pw_acc(src + (size_t)b * SAMP, W, co0, hw, a2);
        #pragma unroll
        for (int k = 0; k < 8; ++k) {
            acc[k].x = fmaf(gs, a2[k].x, acc[k].x);
            acc[k].y = fmaf(gs, a2[k].y, acc[k].y);
        }
    }

    // pools + skip term and single store
    int h = hw >> 5, w = hw & 31;
    int lr = h - r0 + 1;
    #pragma unroll
    for (int k = 0; k < 8; ++k) {
        float2 o = acc[k];
        if (haspool) {
            const float* sp = sxp + k * 18 * 32;
            #pragma unroll
            for (int jj = 0; jj < 2; ++jj) {
                int ww = w + jj;
                float mx = -3.4e38f, sm = 0.f;
                int cnt = 0;
                #pragma unroll
                for (int dh = -1; dh <= 1; ++dh) {
                    int ih = h + dh;
                    if ((unsigned)ih >= HH) continue;
                    #pragma unroll
                    for (int dw = -1; dw <= 1; ++dw) {
                        int iw = ww + dw;
                        if ((unsigned)iw >= WW) continue;
                        float v = sp[(lr + dh) * 32 + iw];
                        mx = fmaxf(mx, v);
                        sm += v;
                        ++cnt;
                    }
                }
                float pv = g1 * mx + g2 * (sm / (float)cnt) + g3 * sp[lr * 32 + ww];
                if (jj == 0) o.x += pv; else o.y += pv;
            }
        }
        *(float2*)(out + (size_t)(b * CC + co0 + k) * PLANE + hw) = o;
    }
}

// ---------------------------------------------------------------- launch
extern "C" void kernel_launch(void* const* d_in, const int* in_sizes, int n_in,
                              void* d_out, int out_size, void* d_ws, size_t ws_size,
                              hipStream_t stream) {
    const float* x      = (const float*)d_in[0];
    const float* wlog   = (const float*)d_in[1];
    const float* sc3_d1 = (const float*)d_in[2];
    const float* sc3_p1 = (const float*)d_in[3];
    const float* sc3_d2 = (const float*)d_in[4];
    const float* sc3_p2 = (const float*)d_in[5];
    const float* sc5_d1 = (const float*)d_in[6];
    const float* sc5_p1 = (const float*)d_in[7];
    const float* sc5_d2 = (const float*)d_in[8];
    const float* sc5_p2 = (const float*)d_in[9];
    const float* dc3_d  = (const float*)d_in[10];
    const float* dc3_p  = (const float*)d_in[11];
    const float* dc5_d  = (const float*)d_in[12];
    const float* dc5_p  = (const float*)d_in[13];
    const void* topp    = d_in[14];

    float* out  = (float*)d_out;
    float* outw = out + NOUT0;

    float* gates = (float*)d_ws;
    int*   cnum  = (int*)((char*)d_ws + 2048);
    int*   cops  = (int*)((char*)d_ws + 2304);
    unsigned short* base = (unsigned short*)((char*)d_ws + 4096);
    unsigned short* A4 = base;
    unsigned short* A5 = base + (size_t)NOUT0;
    unsigned short* B4 = base + (size_t)NOUT0 * 2;
    unsigned short* B5 = base + (size_t)NOUT0 * 3;
    unsigned short* P4 = base + (size_t)NOUT0 * 4;
    unsigned short* P5 = base + (size_t)NOUT0 * 5;
    unsigned short* P6 = base + (size_t)NOUT0 * 6;
    unsigned short* P7 = base + (size_t)NOUT0 * 7;

    k_gates<<<1, 64, 0, stream>>>(wlog, topp, gates, cnum, cops, outw);
    k_dw_first<<<BB * CC, 256, 0, stream>>>(x, sc3_d1, sc5_d1, dc3_d, dc5_d,
                                            gates, A4, A5, P6, P7);
    k_pw_mid<<<2 * BB * 32, 256, 0, stream>>>(A4, A5, sc3_p1, sc5_p1, gates, B4, B5);
    k_dw_second<<<BB * CC, 256, 0, stream>>>(B4, B5, sc3_d2, sc5_d2, gates, P4, P5);
    k_pw_final<<<BB * 32, 256, 0, stream>>>(x, P4, P5, P6, P7,
                                            sc3_p2, sc5_p2, dc3_p, dc5_p,
                                            gates, cnum, cops, out);
}